// Round 2
// baseline (581.754 us; speedup 1.0000x reference)
//
#include <hip/hip_runtime.h>

// out = mean( (rowdot(x,y) / (||x||_F * ||y||_F) * RAD2DEG)^2 )
// N=65536 rows, D=1024 cols, fp32. 512 MiB of reads -> memory-bound.
// Single fused kernel: per-wave 8 rows, deferred batched reductions,
// device-scope atomic accumulation + last-block final compute.

#define RAD2DEG 57.29577951308232f

constexpr int N_ROWS  = 65536;
constexpr int D_COLS  = 1024;
constexpr int BLOCKS  = 2048;
constexpr int THREADS = 256;
constexpr int WAVES_PER_BLOCK = THREADS / 64;        // 4
constexpr int NWAVE   = BLOCKS * WAVES_PER_BLOCK;    // 8192
constexpr int ROWS_PER_WAVE = N_ROWS / NWAVE;        // 8

__global__ __launch_bounds__(THREADS) void ang_fused(
        const float* __restrict__ x,
        const float* __restrict__ y,
        float* __restrict__ acc,      // d_ws: acc[0..2] = {sum dot^2, sum x^2, sum y^2}
        int*   __restrict__ counter,  // d_ws: arrival counter
        float* __restrict__ out) {
    const int lane  = threadIdx.x & 63;
    const int wid   = threadIdx.x >> 6;
    const int gwave = blockIdx.x * WAVES_PER_BLOCK + wid;

    float x2 = 0.0f, y2 = 0.0f;
    float dot[ROWS_PER_WAVE];

    // Load loop: 8 rows fully unrolled, NO cross-lane ops inside -> loads of
    // row i+1 pipeline behind row i's FMAs. Rows reversed so the most
    // recently restored (L3-resident) data is read first.
#pragma unroll
    for (int i = 0; i < ROWS_PER_WAVE; ++i) {
        const int row = (N_ROWS - 1) - (gwave + i * NWAVE);
        const float4* __restrict__ xr = (const float4*)(x + (size_t)row * D_COLS);
        const float4* __restrict__ yr = (const float4*)(y + (size_t)row * D_COLS);
        float d = 0.0f;
#pragma unroll
        for (int k = 0; k < 4; ++k) {
            float4 a = xr[lane + 64 * k];   // 64 lanes x 16B = 1 KiB coalesced
            float4 b = yr[lane + 64 * k];
            d  = fmaf(a.x, b.x, d);
            d  = fmaf(a.y, b.y, d);
            d  = fmaf(a.z, b.z, d);
            d  = fmaf(a.w, b.w, d);
            x2 = fmaf(a.x, a.x, x2);
            x2 = fmaf(a.y, a.y, x2);
            x2 = fmaf(a.z, a.z, x2);
            x2 = fmaf(a.w, a.w, x2);
            y2 = fmaf(b.x, b.x, y2);
            y2 = fmaf(b.y, b.y, y2);
            y2 = fmaf(b.z, b.z, y2);
            y2 = fmaf(b.w, b.w, y2);
        }
        dot[i] = d;
    }

    // Batched wave reductions: 8 independent 6-deep chains interleave (ILP),
    // instead of 8 serialized 6-deep chains in the load loop.
#pragma unroll
    for (int off = 32; off > 0; off >>= 1) {
#pragma unroll
        for (int i = 0; i < ROWS_PER_WAVE; ++i)
            dot[i] += __shfl_xor(dot[i], off, 64);
        x2 += __shfl_xor(x2, off, 64);
        y2 += __shfl_xor(y2, off, 64);
    }
    float dsq = 0.0f;
#pragma unroll
    for (int i = 0; i < ROWS_PER_WAVE; ++i)
        dsq = fmaf(dot[i], dot[i], dsq);

    // Block reduce (4 waves) via LDS.
    __shared__ float s[WAVES_PER_BLOCK][3];
    if (lane == 0) {
        s[wid][0] = dsq;
        s[wid][1] = x2;
        s[wid][2] = y2;
    }
    __syncthreads();
    if (threadIdx.x == 0) {
        float a = 0.0f, b = 0.0f, c = 0.0f;
#pragma unroll
        for (int w = 0; w < WAVES_PER_BLOCK; ++w) {
            a += s[w][0];
            b += s[w][1];
            c += s[w][2];
        }
        // Device-scope float atomics: coherent across XCDs.
        atomicAdd(&acc[0], a);
        atomicAdd(&acc[1], b);
        atomicAdd(&acc[2], c);
        __threadfence();
        const int old = atomicAdd(counter, 1);
        if (old == BLOCKS - 1) {
            // All blocks' RMWs to acc precede their counter RMW; reading via
            // RMW hits the same coherence point -> sees the final sums.
            float ta = atomicAdd(&acc[0], 0.0f);
            float tb = atomicAdd(&acc[1], 0.0f);
            float tc = atomicAdd(&acc[2], 0.0f);
            out[0] = ta / (tb * tc) * (RAD2DEG * RAD2DEG / (float)N_ROWS);
        }
    }
}

extern "C" void kernel_launch(void* const* d_in, const int* in_sizes, int n_in,
                              void* d_out, int out_size, void* d_ws, size_t ws_size,
                              hipStream_t stream) {
    const float* x = (const float*)d_in[0];
    const float* y = (const float*)d_in[1];
    float* out     = (float*)d_out;
    float* acc     = (float*)d_ws;           // 3 floats
    int*   counter = (int*)d_ws + 3;         // 1 int

    hipMemsetAsync(d_ws, 0, 16, stream);     // zero acc + counter (capture-legal)
    ang_fused<<<BLOCKS, THREADS, 0, stream>>>(x, y, acc, counter, out);
}

// Round 3
// 499.077 us; speedup vs baseline: 1.1657x; 1.1657x over previous
//
#include <hip/hip_runtime.h>

// out = mean( (rowdot(x,y) / (||x||_F * ||y||_F) * RAD2DEG)^2 )
// N=65536 rows, D=1024, fp32. Memory-bound; limiter so far is per-wave MLP
// (VGPR=24 -> only 2 loads in flight). This version batches a full row
// (8 independent float4 loads) into explicit register arrays before any use.

#define RAD2DEG 57.29577951308232f

constexpr int N_ROWS  = 65536;
constexpr int D_COLS  = 1024;            // = 256 float4 per row
constexpr int BLOCKS  = 2048;
constexpr int THREADS = 256;
constexpr int WPB     = THREADS / 64;    // 4 waves/block
constexpr int NWAVE   = BLOCKS * WPB;    // 8192 waves
constexpr int RPW     = N_ROWS / NWAVE;  // 8 rows/wave

// 8 waves/EU floor -> VGPR cap 64; design fits (~32 data + 8 dot + misc).
__global__ __launch_bounds__(THREADS, 8) void ang_partials(
        const float* __restrict__ x,
        const float* __restrict__ y,
        float* __restrict__ partials) {
    const int lane  = threadIdx.x & 63;
    const int wid   = threadIdx.x >> 6;
    const int gwave = blockIdx.x * WPB + wid;

    float x2 = 0.0f, y2 = 0.0f;
    float dot[RPW];

#pragma unroll 1   // keep rolled: bounded VGPR pressure, 8 loads in flight
    for (int i = 0; i < RPW; ++i) {
        const int row = gwave + i * NWAVE;
        const float4* __restrict__ xr = (const float4*)(x + (size_t)row * D_COLS);
        const float4* __restrict__ yr = (const float4*)(y + (size_t)row * D_COLS);

        // Batch: 8 independent 1KiB-coalesced loads, no consumer in between.
        float4 ax[4], ay[4];
#pragma unroll
        for (int k = 0; k < 4; ++k) ax[k] = xr[lane + 64 * k];
#pragma unroll
        for (int k = 0; k < 4; ++k) ay[k] = yr[lane + 64 * k];

        float d = 0.0f;
#pragma unroll
        for (int k = 0; k < 4; ++k) {
            d  = fmaf(ax[k].x, ay[k].x, d);
            d  = fmaf(ax[k].y, ay[k].y, d);
            d  = fmaf(ax[k].z, ay[k].z, d);
            d  = fmaf(ax[k].w, ay[k].w, d);
            x2 = fmaf(ax[k].x, ax[k].x, x2);
            x2 = fmaf(ax[k].y, ax[k].y, x2);
            x2 = fmaf(ax[k].z, ax[k].z, x2);
            x2 = fmaf(ax[k].w, ax[k].w, x2);
            y2 = fmaf(ay[k].x, ay[k].x, y2);
            y2 = fmaf(ay[k].y, ay[k].y, y2);
            y2 = fmaf(ay[k].z, ay[k].z, y2);
            y2 = fmaf(ay[k].w, ay[k].w, y2);
        }
        dot[i] = d;
    }

    // Deferred reductions: 10 independent butterfly chains interleave.
#pragma unroll
    for (int off = 32; off > 0; off >>= 1) {
#pragma unroll
        for (int i = 0; i < RPW; ++i)
            dot[i] += __shfl_xor(dot[i], off, 64);
        x2 += __shfl_xor(x2, off, 64);
        y2 += __shfl_xor(y2, off, 64);
    }
    float dsq = 0.0f;
#pragma unroll
    for (int i = 0; i < RPW; ++i)
        dsq = fmaf(dot[i], dot[i], dsq);

    __shared__ float s[WPB][3];
    if (lane == 0) {
        s[wid][0] = dsq;
        s[wid][1] = x2;
        s[wid][2] = y2;
    }
    __syncthreads();
    if (threadIdx.x == 0) {
        float a = 0.0f, b = 0.0f, c = 0.0f;
#pragma unroll
        for (int w = 0; w < WPB; ++w) {
            a += s[w][0];
            b += s[w][1];
            c += s[w][2];
        }
        partials[blockIdx.x * 3 + 0] = a;
        partials[blockIdx.x * 3 + 1] = b;
        partials[blockIdx.x * 3 + 2] = c;
    }
}

__global__ __launch_bounds__(256) void ang_final(
        const float* __restrict__ partials,
        float* __restrict__ out,
        int nblocks) {
    const int lane = threadIdx.x & 63;
    const int wid  = threadIdx.x >> 6;

    float a = 0.0f, b = 0.0f, c = 0.0f;
    for (int i = threadIdx.x; i < nblocks; i += 256) {
        a += partials[i * 3 + 0];
        b += partials[i * 3 + 1];
        c += partials[i * 3 + 2];
    }
#pragma unroll
    for (int off = 32; off > 0; off >>= 1) {
        a += __shfl_xor(a, off, 64);
        b += __shfl_xor(b, off, 64);
        c += __shfl_xor(c, off, 64);
    }
    __shared__ float s[4][3];
    if (lane == 0) {
        s[wid][0] = a;
        s[wid][1] = b;
        s[wid][2] = c;
    }
    __syncthreads();
    if (threadIdx.x == 0) {
        float ta = 0.0f, tb = 0.0f, tc = 0.0f;
#pragma unroll
        for (int w = 0; w < 4; ++w) {
            ta += s[w][0];
            tb += s[w][1];
            tc += s[w][2];
        }
        out[0] = ta / (tb * tc) * (RAD2DEG * RAD2DEG / (float)N_ROWS);
    }
}

extern "C" void kernel_launch(void* const* d_in, const int* in_sizes, int n_in,
                              void* d_out, int out_size, void* d_ws, size_t ws_size,
                              hipStream_t stream) {
    const float* x = (const float*)d_in[0];
    const float* y = (const float*)d_in[1];
    float* out      = (float*)d_out;
    float* partials = (float*)d_ws;   // BLOCKS*3 floats

    ang_partials<<<BLOCKS, THREADS, 0, stream>>>(x, y, partials);
    ang_final<<<1, 256, 0, stream>>>(partials, out, BLOCKS);
}

// Round 5
// 467.856 us; speedup vs baseline: 1.2434x; 1.0667x over previous
//
#include <hip/hip_runtime.h>

// out = mean( (rowdot(x,y) / (||x||_F * ||y||_F) * RAD2DEG)^2 )
// N=65536 rows, D=1024, fp32. Memory-bound. R3 showed per-wave MLP is NOT
// the limiter (256KB/CU in flight >> 9KB needed); theory is dirty-L3
// writeback interference from the harness restore. Nontemporal loads
// (no-allocate) avoid evicting dirty restore data during our dispatch.

#define RAD2DEG 57.29577951308232f

typedef float fx4 __attribute__((ext_vector_type(4)));  // native vec type:
// __builtin_nontemporal_load requires scalar/native-vector element pointers.

constexpr int N_ROWS  = 65536;
constexpr int D_COLS  = 1024;            // = 256 float4 per row
constexpr int BLOCKS  = 2048;
constexpr int THREADS = 256;
constexpr int WPB     = THREADS / 64;    // 4 waves/block
constexpr int NWAVE   = BLOCKS * WPB;    // 8192 waves
constexpr int RPW     = N_ROWS / NWAVE;  // 8 rows/wave

__global__ __launch_bounds__(THREADS, 8) void ang_partials(
        const float* __restrict__ x,
        const float* __restrict__ y,
        float* __restrict__ partials) {
    const int lane  = threadIdx.x & 63;
    const int wid   = threadIdx.x >> 6;
    const int gwave = blockIdx.x * WPB + wid;

    float x2 = 0.0f, y2 = 0.0f;
    float dot[RPW];

#pragma unroll 1   // rolled: bounded VGPR pressure, 8 loads in flight
    for (int i = 0; i < RPW; ++i) {
        const int row = gwave + i * NWAVE;
        const fx4* __restrict__ xr = (const fx4*)(x + (size_t)row * D_COLS);
        const fx4* __restrict__ yr = (const fx4*)(y + (size_t)row * D_COLS);

        // 8 independent 1KiB-coalesced NONTEMPORAL loads (nt = no-allocate:
        // don't evict L3-resident dirty restore data; hits still serve).
        fx4 ax[4], ay[4];
#pragma unroll
        for (int k = 0; k < 4; ++k)
            ax[k] = __builtin_nontemporal_load(&xr[lane + 64 * k]);
#pragma unroll
        for (int k = 0; k < 4; ++k)
            ay[k] = __builtin_nontemporal_load(&yr[lane + 64 * k]);

        float d = 0.0f;
#pragma unroll
        for (int k = 0; k < 4; ++k) {
            d  = fmaf(ax[k].x, ay[k].x, d);
            d  = fmaf(ax[k].y, ay[k].y, d);
            d  = fmaf(ax[k].z, ay[k].z, d);
            d  = fmaf(ax[k].w, ay[k].w, d);
            x2 = fmaf(ax[k].x, ax[k].x, x2);
            x2 = fmaf(ax[k].y, ax[k].y, x2);
            x2 = fmaf(ax[k].z, ax[k].z, x2);
            x2 = fmaf(ax[k].w, ax[k].w, x2);
            y2 = fmaf(ay[k].x, ay[k].x, y2);
            y2 = fmaf(ay[k].y, ay[k].y, y2);
            y2 = fmaf(ay[k].z, ay[k].z, y2);
            y2 = fmaf(ay[k].w, ay[k].w, y2);
        }
        dot[i] = d;
    }

    // Deferred reductions: 10 independent butterfly chains interleave.
#pragma unroll
    for (int off = 32; off > 0; off >>= 1) {
#pragma unroll
        for (int i = 0; i < RPW; ++i)
            dot[i] += __shfl_xor(dot[i], off, 64);
        x2 += __shfl_xor(x2, off, 64);
        y2 += __shfl_xor(y2, off, 64);
    }
    float dsq = 0.0f;
#pragma unroll
    for (int i = 0; i < RPW; ++i)
        dsq = fmaf(dot[i], dot[i], dsq);

    __shared__ float s[WPB][3];
    if (lane == 0) {
        s[wid][0] = dsq;
        s[wid][1] = x2;
        s[wid][2] = y2;
    }
    __syncthreads();
    if (threadIdx.x == 0) {
        float a = 0.0f, b = 0.0f, c = 0.0f;
#pragma unroll
        for (int w = 0; w < WPB; ++w) {
            a += s[w][0];
            b += s[w][1];
            c += s[w][2];
        }
        partials[blockIdx.x * 3 + 0] = a;
        partials[blockIdx.x * 3 + 1] = b;
        partials[blockIdx.x * 3 + 2] = c;
    }
}

__global__ __launch_bounds__(256) void ang_final(
        const float* __restrict__ partials,
        float* __restrict__ out,
        int nblocks) {
    const int lane = threadIdx.x & 63;
    const int wid  = threadIdx.x >> 6;

    float a = 0.0f, b = 0.0f, c = 0.0f;
    for (int i = threadIdx.x; i < nblocks; i += 256) {
        a += partials[i * 3 + 0];
        b += partials[i * 3 + 1];
        c += partials[i * 3 + 2];
    }
#pragma unroll
    for (int off = 32; off > 0; off >>= 1) {
        a += __shfl_xor(a, off, 64);
        b += __shfl_xor(b, off, 64);
        c += __shfl_xor(c, off, 64);
    }
    __shared__ float s[4][3];
    if (lane == 0) {
        s[wid][0] = a;
        s[wid][1] = b;
        s[wid][2] = c;
    }
    __syncthreads();
    if (threadIdx.x == 0) {
        float ta = 0.0f, tb = 0.0f, tc = 0.0f;
#pragma unroll
        for (int w = 0; w < 4; ++w) {
            ta += s[w][0];
            tb += s[w][1];
            tc += s[w][2];
        }
        out[0] = ta / (tb * tc) * (RAD2DEG * RAD2DEG / (float)N_ROWS);
    }
}

extern "C" void kernel_launch(void* const* d_in, const int* in_sizes, int n_in,
                              void* d_out, int out_size, void* d_ws, size_t ws_size,
                              hipStream_t stream) {
    const float* x = (const float*)d_in[0];
    const float* y = (const float*)d_in[1];
    float* out      = (float*)d_out;
    float* partials = (float*)d_ws;   // BLOCKS*3 floats

    ang_partials<<<BLOCKS, THREADS, 0, stream>>>(x, y, partials);
    ang_final<<<1, 256, 0, stream>>>(partials, out, BLOCKS);
}